// Round 1
// 1342.818 us; speedup vs baseline: 1.3483x; 1.3483x over previous
//
#include <hip/hip_runtime.h>

#define RSCALE 0.17677669529663687f   // 1/sqrt(32)

typedef __attribute__((ext_vector_type(8))) short bf16x8;
typedef __attribute__((ext_vector_type(4))) float f32x4;

__device__ __forceinline__ float bf2f(unsigned short u) {
    return __uint_as_float(((unsigned)u) << 16);
}
__device__ __forceinline__ unsigned short f2bf(float f) {
    unsigned u = __float_as_uint(f);
    u += 0x7FFFu + ((u >> 16) & 1u);   // round-to-nearest-even
    return (unsigned short)(u >> 16);
}

// ---------------------------------------------------------------------------
// Kernel 1: fused weights, TRANSPOSED + bf16 for the MFMA GEMM.
// Wt_p [1024][256] bf16 : rows = [Wk_p | Wv_p | Wq_p@R_writes | Wq_p@R_cites]^T
// Wt_a [768][256]  bf16 : rows = [Wk_a | Wv_a | Wq_a@R_writtenby]^T
// bcat_* stay f32.
// ---------------------------------------------------------------------------
__global__ __launch_bounds__(256) void prep_weights(
    const float* __restrict__ Wk_p, const float* __restrict__ Wv_p, const float* __restrict__ Wq_p,
    const float* __restrict__ R_w,  const float* __restrict__ R_c,
    const float* __restrict__ bk_p, const float* __restrict__ bv_p, const float* __restrict__ bq_p,
    const float* __restrict__ Wk_a, const float* __restrict__ Wv_a, const float* __restrict__ Wq_a,
    const float* __restrict__ R_wb,
    const float* __restrict__ bk_a, const float* __restrict__ bv_a, const float* __restrict__ bq_a,
    unsigned short* __restrict__ Wt_p, float* __restrict__ bcat_p,
    unsigned short* __restrict__ Wt_a, float* __restrict__ bcat_a)
{
    const int WP = 1024 * 256, WA = 768 * 256;
    int tid = blockIdx.x * 256 + threadIdx.x;
    if (tid < WP) {
        int c = tid >> 8, k = tid & 255;
        float v;
        if (c < 256)       v = Wk_p[k * 256 + c];
        else if (c < 512)  v = Wv_p[k * 256 + (c - 256)];
        else {
            int f = c & 255;
            const float* R = (c < 768) ? R_w : R_c;
            int h = f >> 5, fd = f & 31;
            float s = 0.f;
            #pragma unroll
            for (int d = 0; d < 32; d++) s += Wq_p[k * 256 + h * 32 + d] * R[(h * 32 + d) * 32 + fd];
            v = s;
        }
        Wt_p[tid] = f2bf(v);
    } else if (tid < WP + WA) {
        int t2 = tid - WP;
        int c = t2 >> 8, k = t2 & 255;
        float v;
        if (c < 256)       v = Wk_a[k * 256 + c];
        else if (c < 512)  v = Wv_a[k * 256 + (c - 256)];
        else {
            int f = c - 512, h = f >> 5, fd = f & 31;
            float s = 0.f;
            #pragma unroll
            for (int d = 0; d < 32; d++) s += Wq_a[k * 256 + h * 32 + d] * R_wb[(h * 32 + d) * 32 + fd];
            v = s;
        }
        Wt_a[t2] = f2bf(v);
    } else if (tid < WP + WA + 1024) {
        int c = tid - WP - WA;
        float v;
        if (c < 256)       v = bk_p[c];
        else if (c < 512)  v = bv_p[c - 256];
        else {
            int f = c & 255;
            const float* R = (c < 768) ? R_w : R_c;
            int h = f >> 5, fd = f & 31;
            float s = 0.f;
            #pragma unroll
            for (int d = 0; d < 32; d++) s += bq_p[h * 32 + d] * R[(h * 32 + d) * 32 + fd];
            v = s;
        }
        bcat_p[c] = v;
    } else if (tid < WP + WA + 1024 + 768) {
        int c = tid - WP - WA - 1024;
        float v;
        if (c < 256)       v = bk_a[c];
        else if (c < 512)  v = bv_a[c - 256];
        else {
            int f = c - 512, h = f >> 5, fd = f & 31;
            float s = 0.f;
            #pragma unroll
            for (int d = 0; d < 32; d++) s += bq_a[h * 32 + d] * R_wb[(h * 32 + d) * 32 + fd];
            v = s;
        }
        bcat_a[c] = v;
    }
}

// ---------------------------------------------------------------------------
// Kernel 1b: Wo transposed to bf16: Wto[c][k] = Wo[k][c].
// ---------------------------------------------------------------------------
__global__ __launch_bounds__(256) void prep_wo(
    const float* __restrict__ Wo_p, const float* __restrict__ Wo_a,
    unsigned short* __restrict__ Wto_p, unsigned short* __restrict__ Wto_a)
{
    int tid = blockIdx.x * 256 + threadIdx.x;   // 0..131071
    int which = tid >> 16, i = tid & 65535;
    int c = i >> 8, k = i & 255;
    const float* W = which ? Wo_a : Wo_p;
    unsigned short* o = which ? Wto_a : Wto_p;
    o[i] = f2bf(W[k * 256 + c]);
}

// ---------------------------------------------------------------------------
// Kernel 2: MFMA GEMM.  Y[bf16, nrows x ncols] = X[f32] @ Wt^T + bias.
// (unchanged)
// ---------------------------------------------------------------------------
__global__ __launch_bounds__(256) void gemm_mfma(
    const float* __restrict__ X, const unsigned short* __restrict__ Wt,
    const float* __restrict__ bias, unsigned short* __restrict__ Y,
    int nrows, int ncols)
{
    __shared__ unsigned short As[128][72];
    __shared__ unsigned short Bs[128][72];
    const int t = threadIdx.x;
    const int wave = t >> 6, lane = t & 63;
    const int wm = wave >> 1, wn = wave & 1;
    const int row0 = blockIdx.y * 128, col0 = blockIdx.x * 128;
    const int lquad = lane >> 4, lmod = lane & 15;

    f32x4 acc[4][4];
    #pragma unroll
    for (int i = 0; i < 4; i++)
        #pragma unroll
        for (int j = 0; j < 4; j++) acc[i][j] = (f32x4){0.f, 0.f, 0.f, 0.f};

    for (int k0 = 0; k0 < 256; k0 += 64) {
        #pragma unroll
        for (int p = 0; p < 8; p++) {
            int r = p * 16 + (t >> 4);
            int c4 = (t & 15) * 4;
            float4 v = make_float4(0.f, 0.f, 0.f, 0.f);
            if (row0 + r < nrows) v = *(const float4*)&X[(size_t)(row0 + r) * 256 + k0 + c4];
            ushort4 pk;
            pk.x = f2bf(v.x); pk.y = f2bf(v.y); pk.z = f2bf(v.z); pk.w = f2bf(v.w);
            *(ushort4*)&As[r][c4] = pk;
        }
        #pragma unroll
        for (int p = 0; p < 4; p++) {
            int r = p * 32 + (t >> 3);
            int c8 = (t & 7) * 8;
            float4 w = *(const float4*)&Wt[(size_t)(col0 + r) * 256 + k0 + c8];
            *(float4*)&Bs[r][c8] = w;
        }
        __syncthreads();
        #pragma unroll
        for (int ks = 0; ks < 2; ks++) {
            bf16x8 af[4], bfr[4];
            #pragma unroll
            for (int i = 0; i < 4; i++)
                af[i] = *(const bf16x8*)&As[wm * 64 + i * 16 + lmod][ks * 32 + lquad * 8];
            #pragma unroll
            for (int j = 0; j < 4; j++)
                bfr[j] = *(const bf16x8*)&Bs[wn * 64 + j * 16 + lmod][ks * 32 + lquad * 8];
            #pragma unroll
            for (int i = 0; i < 4; i++)
                #pragma unroll
                for (int j = 0; j < 4; j++)
                    acc[i][j] = __builtin_amdgcn_mfma_f32_16x16x32_bf16(af[i], bfr[j], acc[i][j], 0, 0, 0);
        }
        __syncthreads();
    }

    float bj[4];
    #pragma unroll
    for (int j = 0; j < 4; j++) bj[j] = bias[col0 + wn * 64 + j * 16 + lmod];
    #pragma unroll
    for (int i = 0; i < 4; i++) {
        int rbase = row0 + wm * 64 + i * 16 + lquad * 4;
        #pragma unroll
        for (int rg = 0; rg < 4; rg++) {
            int r = rbase + rg;
            if (r < nrows) {
                #pragma unroll
                for (int j = 0; j < 4; j++) {
                    int c = col0 + wn * 64 + j * 16 + lmod;
                    Y[(size_t)r * ncols + c] = f2bf(acc[i][j][rg] + bj[j]);
                }
            }
        }
    }
}

// ---------------------------------------------------------------------------
// CSR build (unchanged).
// ---------------------------------------------------------------------------
__global__ __launch_bounds__(256) void hist_kernel(const int* __restrict__ ei, int E,
                                                   int* __restrict__ cnt)
{
    int i = blockIdx.x * 256 + threadIdx.x;
    if (i < E) atomicAdd(&cnt[ei[E + i]], 1);
}

__global__ __launch_bounds__(256) void scan1(const int* __restrict__ cnt, int n,
                                             int* __restrict__ bsum)
{
    __shared__ int s[256];
    int b = blockIdx.x, t = threadIdx.x;
    int i0 = b * 1024 + t * 4, v = 0;
    if (i0 + 3 < n) {
        int4 q = *(const int4*)&cnt[i0];
        v = q.x + q.y + q.z + q.w;
    } else {
        for (int j = 0; j < 4; j++) if (i0 + j < n) v += cnt[i0 + j];
    }
    s[t] = v; __syncthreads();
    for (int off = 128; off > 0; off >>= 1) {
        if (t < off) s[t] += s[t + off];
        __syncthreads();
    }
    if (t == 0) bsum[b] = s[0];
}

__global__ __launch_bounds__(256) void scan2(int* __restrict__ bsum, int nb)
{
    __shared__ int s[256];
    int t = threadIdx.x;
    int v = (t < nb) ? bsum[t] : 0;
    s[t] = v; __syncthreads();
    for (int off = 1; off < 256; off <<= 1) {
        int x = 0;
        if (t >= off) x = s[t - off];
        __syncthreads();
        s[t] += x;
        __syncthreads();
    }
    if (t < nb) bsum[t] = s[t] - v;   // exclusive
}

__global__ __launch_bounds__(256) void scan3(int* __restrict__ cnt, int n,
                                             const int* __restrict__ bsum,
                                             int* __restrict__ row_ptr)
{
    __shared__ int s[256];
    int b = blockIdx.x, t = threadIdx.x;
    int i0 = b * 1024 + t * 4;
    int v[4]; int tot = 0;
    #pragma unroll
    for (int j = 0; j < 4; j++) { v[j] = (i0 + j < n) ? cnt[i0 + j] : 0; tot += v[j]; }
    s[t] = tot; __syncthreads();
    for (int off = 1; off < 256; off <<= 1) {
        int x = 0;
        if (t >= off) x = s[t - off];
        __syncthreads();
        s[t] += x;
        __syncthreads();
    }
    int run = s[t] - tot + bsum[b];
    #pragma unroll
    for (int j = 0; j < 4; j++) {
        int i = i0 + j;
        if (i < n) {
            row_ptr[i] = run;
            cnt[i] = run;      // cursor
            run += v[j];
            if (i == n - 1) row_ptr[n] = run;
        }
    }
}

__global__ __launch_bounds__(256) void scatter_kernel(const int* __restrict__ ei, int E, int rel,
                                                      int* __restrict__ cursor, int* __restrict__ eout)
{
    int i = blockIdx.x * 256 + threadIdx.x;
    if (i < E) {
        int pos = atomicAdd(&cursor[ei[E + i]], 1);
        eout[pos] = (ei[i] << 1) | rel;
    }
}

// ---------------------------------------------------------------------------
// Kernel 3: per-node gather-reduce. Now fuses the /norm division and writes
// agg (f32) directly -- normv buffer and the epilogue division are gone.
// ---------------------------------------------------------------------------
__global__ __launch_bounds__(256) void aggregate_kernel(
    const unsigned short* __restrict__ Ydst, int dstride, int qoff0, int qoff1,
    const unsigned short* __restrict__ Ysrc0, int sstride0,
    const unsigned short* __restrict__ Ysrc1, int sstride1,
    const int* __restrict__ row_ptr, const int* __restrict__ edges,
    int nnodes, float* __restrict__ agg)
{
    const int wave = threadIdx.x >> 6, lane = threadIdx.x & 63;
    const int node = blockIdx.x * 4 + wave;
    if (node >= nnodes) return;

    const ushort4 q0u = *(const ushort4*)&Ydst[(size_t)node * dstride + qoff0 + lane * 4];
    const ushort4 q1u = *(const ushort4*)&Ydst[(size_t)node * dstride + qoff1 + lane * 4];
    const float q0x = bf2f(q0u.x), q0y = bf2f(q0u.y), q0z = bf2f(q0u.z), q0w = bf2f(q0u.w);
    const float q1x = bf2f(q1u.x), q1y = bf2f(q1u.y), q1z = bf2f(q1u.z), q1w = bf2f(q1u.w);

    float a0 = 0.f, a1 = 0.f, a2 = 0.f, a3 = 0.f, hs = 0.f;
    const int beg = row_ptr[node], end = row_ptr[node + 1];
    for (int i = beg; i < end; i++) {
        const int e = edges[i];
        const int rel = e & 1;
        const size_t src = (size_t)(e >> 1);
        const unsigned short* Ys = rel ? Ysrc1 : Ysrc0;
        const int ss = rel ? sstride1 : sstride0;
        const ushort4 ku = *(const ushort4*)&Ys[src * ss + lane * 4];
        const ushort4 vu = *(const ushort4*)&Ys[src * ss + 256 + lane * 4];
        float p = (rel ? q1x : q0x) * bf2f(ku.x) + (rel ? q1y : q0y) * bf2f(ku.y)
                + (rel ? q1z : q0z) * bf2f(ku.z) + (rel ? q1w : q0w) * bf2f(ku.w);
        p += __shfl_xor(p, 1);
        p += __shfl_xor(p, 2);
        p += __shfl_xor(p, 4);
        float sc = fminf(fmaxf(p * RSCALE, -5.f), 5.f);
        float a = expf(sc);
        a0 += bf2f(vu.x) * a;
        a1 += bf2f(vu.y) * a;
        a2 += bf2f(vu.z) * a;
        a3 += bf2f(vu.w) * a;
        hs += a;
    }
    // sum the 8 distinct per-head values (lanes within a group are equal)
    hs += __shfl_xor(hs, 8);
    hs += __shfl_xor(hs, 16);
    hs += __shfl_xor(hs, 32);

    const float inv = 1.f / fmaxf(hs * 0.125f, 1e-8f);
    float4 o = make_float4(a0 * inv, a1 * inv, a2 * inv, a3 * inv);
    *(float4*)&agg[(size_t)node * 256 + lane * 4] = o;
}

// ---------------------------------------------------------------------------
// Kernel 4 (NEW): fused output projection + residual + LayerNorm on MFMA.
// Block = 64 rows x 256 cols (full width), 4 waves; wave w owns cols w*64..+63.
// A (agg, f32) is split hi/lo bf16 on the fly: a ~= hi + lo, two MFMAs into
// the same accumulator -> only Wo's bf16 rounding remains as new error.
// Accumulator -> LDS f32 [64][264] (2-way bank alias only) -> per-wave LN
// over 16 full rows each -> coalesced float4 store. In-place over agg is safe:
// each block fully reads its 64 agg rows (K-loop) before writing them (LN).
// ---------------------------------------------------------------------------
__global__ __launch_bounds__(256) void ogemm_ln_kernel(
    const float* agg,                         // [nrows][256] f32 (aliases out)
    const unsigned short* __restrict__ Wt,    // [256][256] bf16, row = out col
    const float* __restrict__ bo, const float* __restrict__ x,
    const float* __restrict__ g, const float* __restrict__ be,
    float* out, int nrows)
{
    __shared__ __align__(16) char smem[64 * 264 * 4];   // 67.6 KB -> 2 blocks/CU
    unsigned short* As_hi = (unsigned short*)smem;      // [64][72]
    unsigned short* As_lo = As_hi + 64 * 72;            // [64][72]
    unsigned short* Bs    = As_lo + 64 * 72;            // [256][72]
    float* Yo = (float*)smem;                           // [64][264] (reused)

    const int t = threadIdx.x;
    const int wave = t >> 6, lane = t & 63;
    const int lquad = lane >> 4, lmod = lane & 15;
    const int row0 = blockIdx.x * 64;
    const int wcol = wave * 64;

    f32x4 acc[4][4];
    #pragma unroll
    for (int i = 0; i < 4; i++)
        #pragma unroll
        for (int j = 0; j < 4; j++) acc[i][j] = (f32x4){0.f, 0.f, 0.f, 0.f};

    for (int k0 = 0; k0 < 256; k0 += 64) {
        // stage A: 64 rows x 64 f32 -> hi/lo bf16 split
        #pragma unroll
        for (int p = 0; p < 2; p++) {
            int r = p * 32 + (t >> 3);
            int c8 = (t & 7) * 8;
            float4 v0 = make_float4(0.f, 0.f, 0.f, 0.f), v1 = v0;
            if (row0 + r < nrows) {
                v0 = *(const float4*)&agg[(size_t)(row0 + r) * 256 + k0 + c8];
                v1 = *(const float4*)&agg[(size_t)(row0 + r) * 256 + k0 + c8 + 4];
            }
            ushort4 h0, h1, l0, l1;
            h0.x = f2bf(v0.x); l0.x = f2bf(v0.x - bf2f(h0.x));
            h0.y = f2bf(v0.y); l0.y = f2bf(v0.y - bf2f(h0.y));
            h0.z = f2bf(v0.z); l0.z = f2bf(v0.z - bf2f(h0.z));
            h0.w = f2bf(v0.w); l0.w = f2bf(v0.w - bf2f(h0.w));
            h1.x = f2bf(v1.x); l1.x = f2bf(v1.x - bf2f(h1.x));
            h1.y = f2bf(v1.y); l1.y = f2bf(v1.y - bf2f(h1.y));
            h1.z = f2bf(v1.z); l1.z = f2bf(v1.z - bf2f(h1.z));
            h1.w = f2bf(v1.w); l1.w = f2bf(v1.w - bf2f(h1.w));
            *(ushort4*)&As_hi[r * 72 + c8]     = h0;
            *(ushort4*)&As_hi[r * 72 + c8 + 4] = h1;
            *(ushort4*)&As_lo[r * 72 + c8]     = l0;
            *(ushort4*)&As_lo[r * 72 + c8 + 4] = l1;
        }
        // stage B: 256 rows of Wt x 64 bf16
        #pragma unroll
        for (int p = 0; p < 8; p++) {
            int r = p * 32 + (t >> 3);
            int c8 = (t & 7) * 8;
            *(float4*)&Bs[r * 72 + c8] = *(const float4*)&Wt[(size_t)r * 256 + k0 + c8];
        }
        __syncthreads();
        #pragma unroll
        for (int ks = 0; ks < 2; ks++) {
            bf16x8 ah[4], al[4], bfr[4];
            #pragma unroll
            for (int i = 0; i < 4; i++) {
                ah[i] = *(const bf16x8*)&As_hi[(i * 16 + lmod) * 72 + ks * 32 + lquad * 8];
                al[i] = *(const bf16x8*)&As_lo[(i * 16 + lmod) * 72 + ks * 32 + lquad * 8];
            }
            #pragma unroll
            for (int j = 0; j < 4; j++)
                bfr[j] = *(const bf16x8*)&Bs[(wcol + j * 16 + lmod) * 72 + ks * 32 + lquad * 8];
            #pragma unroll
            for (int i = 0; i < 4; i++)
                #pragma unroll
                for (int j = 0; j < 4; j++) {
                    acc[i][j] = __builtin_amdgcn_mfma_f32_16x16x32_bf16(ah[i], bfr[j], acc[i][j], 0, 0, 0);
                    acc[i][j] = __builtin_amdgcn_mfma_f32_16x16x32_bf16(al[i], bfr[j], acc[i][j], 0, 0, 0);
                }
        }
        __syncthreads();
    }

    // C/D layout: col = lane&15, row = (lane>>4)*4 + reg  (m89-verified)
    float bj[4];
    #pragma unroll
    for (int j = 0; j < 4; j++) bj[j] = bo[wcol + j * 16 + lmod];
    #pragma unroll
    for (int i = 0; i < 4; i++)
        #pragma unroll
        for (int j = 0; j < 4; j++)
            #pragma unroll
            for (int rg = 0; rg < 4; rg++)
                Yo[(i * 16 + lquad * 4 + rg) * 264 + wcol + j * 16 + lmod] = acc[i][j][rg] + bj[j];
    __syncthreads();

    // LN: wave handles 16 full rows
    const float4 gv  = *(const float4*)&g[lane * 4];
    const float4 bev = *(const float4*)&be[lane * 4];
    #pragma unroll 1
    for (int ii = 0; ii < 16; ii++) {
        int lr = wave * 16 + ii;
        int r = row0 + lr;
        if (r >= nrows) break;
        float4 y = *(const float4*)&Yo[lr * 264 + lane * 4];
        float4 xv = *(const float4*)&x[(size_t)r * 256 + lane * 4];
        y.x += xv.x; y.y += xv.y; y.z += xv.z; y.w += xv.w;
        float sum = y.x + y.y + y.z + y.w;
        for (int o = 1; o < 64; o <<= 1) sum += __shfl_xor(sum, o);
        float m = sum * (1.f / 256.f);
        float d0 = y.x - m, d1 = y.y - m, d2 = y.z - m, d3 = y.w - m;
        float vs = d0 * d0 + d1 * d1 + d2 * d2 + d3 * d3;
        for (int o = 1; o < 64; o <<= 1) vs += __shfl_xor(vs, o);
        float rstd = rsqrtf(vs * (1.f / 256.f) + 1e-5f);
        float4 o4;
        o4.x = d0 * rstd * gv.x + bev.x;
        o4.y = d1 * rstd * gv.y + bev.y;
        o4.z = d2 * rstd * gv.z + bev.z;
        o4.w = d3 * rstd * gv.w + bev.w;
        *(float4*)&out[(size_t)r * 256 + lane * 4] = o4;
    }
}

// ---------------------------------------------------------------------------
extern "C" void kernel_launch(void* const* d_in, const int* in_sizes, int n_in,
                              void* d_out, int out_size, void* d_ws, size_t ws_size,
                              hipStream_t stream)
{
    const float* x_p  = (const float*)d_in[0];
    const float* x_a  = (const float*)d_in[1];
    const float* Wk_p = (const float*)d_in[2];
    const float* bk_p = (const float*)d_in[3];
    const float* Wq_p = (const float*)d_in[4];
    const float* bq_p = (const float*)d_in[5];
    const float* Wv_p = (const float*)d_in[6];
    const float* bv_p = (const float*)d_in[7];
    const float* Wo_p = (const float*)d_in[8];
    const float* bo_p = (const float*)d_in[9];
    const float* g_p  = (const float*)d_in[10];
    const float* be_p = (const float*)d_in[11];
    const float* Wk_a = (const float*)d_in[12];
    const float* bk_a = (const float*)d_in[13];
    const float* Wq_a = (const float*)d_in[14];
    const float* bq_a = (const float*)d_in[15];
    const float* Wv_a = (const float*)d_in[16];
    const float* bv_a = (const float*)d_in[17];
    const float* Wo_a = (const float*)d_in[18];
    const float* bo_a = (const float*)d_in[19];
    const float* g_a  = (const float*)d_in[20];
    const float* be_a = (const float*)d_in[21];
    const float* R_w  = (const float*)d_in[22];
    const int*   ei_w = (const int*)d_in[23];
    const float* R_c  = (const float*)d_in[24];
    const int*   ei_c = (const int*)d_in[25];
    const float* R_wb = (const float*)d_in[26];
    const int*   ei_wb= (const int*)d_in[27];

    const int N   = in_sizes[0] / 256;
    const int Ew  = in_sizes[23] / 2;
    const int Ec  = in_sizes[25] / 2;
    const int Ewb = in_sizes[27] / 2;

    size_t off = 0;
    auto walloc = [&](size_t bytes) {
        void* p = (char*)d_ws + off;
        off += (bytes + 255) & ~(size_t)255;
        return p;
    };
    unsigned short* Wt_p = (unsigned short*)walloc((size_t)1024 * 256 * 2);
    unsigned short* Wt_a = (unsigned short*)walloc((size_t)768 * 256 * 2);
    unsigned short* Wto_p = (unsigned short*)walloc((size_t)256 * 256 * 2);
    unsigned short* Wto_a = (unsigned short*)walloc((size_t)256 * 256 * 2);
    float* bcat_p = (float*)walloc(1024 * 4);
    float* bcat_a = (float*)walloc(768 * 4);
    unsigned short* Y_p = (unsigned short*)walloc((size_t)N * 1024 * 2);
    unsigned short* Y_a = (unsigned short*)walloc((size_t)N * 768 * 2);
    int* cnt_p = (int*)walloc((size_t)N * 4);        // histogram -> cursor
    int* rp_p  = (int*)walloc((size_t)(N + 1) * 4);
    int* e_p   = (int*)walloc((size_t)(Ew + Ec) * 4);
    int* cnt_a = (int*)walloc((size_t)N * 4);
    int* rp_a  = (int*)walloc((size_t)(N + 1) * 4);
    int* e_a   = (int*)walloc((size_t)Ewb * 4);
    int* bsum  = (int*)walloc(1024 * 4);

    // agg scratch lives in d_out and is consumed/overwritten in place by the
    // fused output-projection+LN kernel.
    float* agg_p = (float*)d_out;
    float* agg_a = (float*)d_out + (size_t)N * 256;

    const int nb = (N + 1023) / 1024;   // scan blocks (98 for N=100k)

    hipMemsetAsync(cnt_p, 0, (size_t)N * 4, stream);
    hipMemsetAsync(cnt_a, 0, (size_t)N * 4, stream);

    {
        int total = 1024 * 256 + 768 * 256 + 1024 + 768;
        prep_weights<<<(total + 255) / 256, 256, 0, stream>>>(
            Wk_p, Wv_p, Wq_p, R_w, R_c, bk_p, bv_p, bq_p,
            Wk_a, Wv_a, Wq_a, R_wb, bk_a, bv_a, bq_a,
            Wt_p, bcat_p, Wt_a, bcat_a);
        prep_wo<<<(2 * 256 * 256) / 256, 256, 0, stream>>>(Wo_p, Wo_a, Wto_p, Wto_a);
    }

    // histograms (independent of GEMMs)
    hist_kernel<<<(Ew + 255) / 256, 256, 0, stream>>>(ei_w, Ew, cnt_p);
    hist_kernel<<<(Ec + 255) / 256, 256, 0, stream>>>(ei_c, Ec, cnt_p);
    hist_kernel<<<(Ewb + 255) / 256, 256, 0, stream>>>(ei_wb, Ewb, cnt_a);

    // projections (MFMA)
    gemm_mfma<<<dim3(1024 / 128, (N + 127) / 128), 256, 0, stream>>>(x_p, Wt_p, bcat_p, Y_p, N, 1024);
    gemm_mfma<<<dim3(768 / 128,  (N + 127) / 128), 256, 0, stream>>>(x_a, Wt_a, bcat_a, Y_a, N, 768);

    // CSR: papers
    scan1<<<nb, 256, 0, stream>>>(cnt_p, N, bsum);
    scan2<<<1, 256, 0, stream>>>(bsum, nb);
    scan3<<<nb, 256, 0, stream>>>(cnt_p, N, bsum, rp_p);
    scatter_kernel<<<(Ew + 255) / 256, 256, 0, stream>>>(ei_w, Ew, 0, cnt_p, e_p);
    scatter_kernel<<<(Ec + 255) / 256, 256, 0, stream>>>(ei_c, Ec, 1, cnt_p, e_p);
    // CSR: authors
    scan1<<<nb, 256, 0, stream>>>(cnt_a, N, bsum);
    scan2<<<1, 256, 0, stream>>>(bsum, nb);
    scan3<<<nb, 256, 0, stream>>>(cnt_a, N, bsum, rp_a);
    scatter_kernel<<<(Ewb + 255) / 256, 256, 0, stream>>>(ei_wb, Ewb, 0, cnt_a, e_a);

    // aggregate: papers receive writes(rel0, src=author) + cites(rel1, src=paper)
    aggregate_kernel<<<(N + 3) / 4, 256, 0, stream>>>(
        Y_p, 1024, 512, 768, Y_a, 768, Y_p, 1024, rp_p, e_p, N, agg_p);
    // authors receive writtenby(rel0, src=paper); Q at col 512 of Y_a
    aggregate_kernel<<<(N + 3) / 4, 256, 0, stream>>>(
        Y_a, 768, 512, 512, Y_p, 1024, Y_p, 1024, rp_a, e_a, N, agg_a);

    // fused output projection + residual + LayerNorm (in-place over agg)
    ogemm_ln_kernel<<<(N + 63) / 64, 256, 0, stream>>>(agg_p, Wto_p, bo_p, x_p, g_p, be_p, agg_p, N);
    ogemm_ln_kernel<<<(N + 63) / 64, 256, 0, stream>>>(agg_a, Wto_a, bo_a, x_a, g_a, be_a, agg_a, N);
}

// Round 2
// 1176.720 us; speedup vs baseline: 1.5386x; 1.1412x over previous
//
#include <hip/hip_runtime.h>

#define RSCALE 0.17677669529663687f   // 1/sqrt(32)

typedef __attribute__((ext_vector_type(8))) short bf16x8;
typedef __attribute__((ext_vector_type(8))) unsigned short u16x8;
typedef __attribute__((ext_vector_type(4))) float f32x4;

__device__ __forceinline__ float bf2f(unsigned short u) {
    return __uint_as_float(((unsigned)u) << 16);
}
__device__ __forceinline__ unsigned short f2bf(float f) {
    unsigned u = __float_as_uint(f);
    u += 0x7FFFu + ((u >> 16) & 1u);   // round-to-nearest-even
    return (unsigned short)(u >> 16);
}

// direct global->LDS async copy, 16 B per lane. LDS dest must be linear:
// wave-uniform base + lane*16 (we pass base + lane*16; lane0's value is the base).
__device__ __forceinline__ void gload_lds16(const unsigned short* g, unsigned short* l) {
    __builtin_amdgcn_global_load_lds(
        (const __attribute__((address_space(1))) void*)g,
        (__attribute__((address_space(3))) void*)l, 16, 0, 0);
}

// ---------------------------------------------------------------------------
// Kernel 0: x (f32) -> bf16 once, so the GEMM A-tiles can be staged with
// global_load_lds and fetch half the bytes.
// ---------------------------------------------------------------------------
__global__ __launch_bounds__(256) void convert_bf16(
    const float* __restrict__ xp, const float* __restrict__ xa,
    unsigned short* __restrict__ bp, unsigned short* __restrict__ ba, int nper)  // nper = N*256/8
{
    const int stride = gridDim.x * 256;
    for (int i = blockIdx.x * 256 + threadIdx.x; i < 2 * nper; i += stride) {
        const float* src = (i < nper) ? xp : xa;
        unsigned short* dst = (i < nper) ? bp : ba;
        const int j = (i < nper) ? i : i - nper;
        float4 v0 = *(const float4*)&src[(size_t)j * 8];
        float4 v1 = *(const float4*)&src[(size_t)j * 8 + 4];
        u16x8 o;
        o[0] = f2bf(v0.x); o[1] = f2bf(v0.y); o[2] = f2bf(v0.z); o[3] = f2bf(v0.w);
        o[4] = f2bf(v1.x); o[5] = f2bf(v1.y); o[6] = f2bf(v1.z); o[7] = f2bf(v1.w);
        *(u16x8*)&dst[(size_t)j * 8] = o;
    }
}

// ---------------------------------------------------------------------------
// Kernel 1: fused weights, TRANSPOSED + bf16 for the MFMA GEMM.
// ---------------------------------------------------------------------------
__global__ __launch_bounds__(256) void prep_weights(
    const float* __restrict__ Wk_p, const float* __restrict__ Wv_p, const float* __restrict__ Wq_p,
    const float* __restrict__ R_w,  const float* __restrict__ R_c,
    const float* __restrict__ bk_p, const float* __restrict__ bv_p, const float* __restrict__ bq_p,
    const float* __restrict__ Wk_a, const float* __restrict__ Wv_a, const float* __restrict__ Wq_a,
    const float* __restrict__ R_wb,
    const float* __restrict__ bk_a, const float* __restrict__ bv_a, const float* __restrict__ bq_a,
    unsigned short* __restrict__ Wt_p, float* __restrict__ bcat_p,
    unsigned short* __restrict__ Wt_a, float* __restrict__ bcat_a)
{
    const int WP = 1024 * 256, WA = 768 * 256;
    int tid = blockIdx.x * 256 + threadIdx.x;
    if (tid < WP) {
        int c = tid >> 8, k = tid & 255;
        float v;
        if (c < 256)       v = Wk_p[k * 256 + c];
        else if (c < 512)  v = Wv_p[k * 256 + (c - 256)];
        else {
            int f = c & 255;
            const float* R = (c < 768) ? R_w : R_c;
            int h = f >> 5, fd = f & 31;
            float s = 0.f;
            #pragma unroll
            for (int d = 0; d < 32; d++) s += Wq_p[k * 256 + h * 32 + d] * R[(h * 32 + d) * 32 + fd];
            v = s;
        }
        Wt_p[tid] = f2bf(v);
    } else if (tid < WP + WA) {
        int t2 = tid - WP;
        int c = t2 >> 8, k = t2 & 255;
        float v;
        if (c < 256)       v = Wk_a[k * 256 + c];
        else if (c < 512)  v = Wv_a[k * 256 + (c - 256)];
        else {
            int f = c - 512, h = f >> 5, fd = f & 31;
            float s = 0.f;
            #pragma unroll
            for (int d = 0; d < 32; d++) s += Wq_a[k * 256 + h * 32 + d] * R_wb[(h * 32 + d) * 32 + fd];
            v = s;
        }
        Wt_a[t2] = f2bf(v);
    } else if (tid < WP + WA + 1024) {
        int c = tid - WP - WA;
        float v;
        if (c < 256)       v = bk_p[c];
        else if (c < 512)  v = bv_p[c - 256];
        else {
            int f = c & 255;
            const float* R = (c < 768) ? R_w : R_c;
            int h = f >> 5, fd = f & 31;
            float s = 0.f;
            #pragma unroll
            for (int d = 0; d < 32; d++) s += bq_p[h * 32 + d] * R[(h * 32 + d) * 32 + fd];
            v = s;
        }
        bcat_p[c] = v;
    } else if (tid < WP + WA + 1024 + 768) {
        int c = tid - WP - WA - 1024;
        float v;
        if (c < 256)       v = bk_a[c];
        else if (c < 512)  v = bv_a[c - 256];
        else {
            int f = c - 512, h = f >> 5, fd = f & 31;
            float s = 0.f;
            #pragma unroll
            for (int d = 0; d < 32; d++) s += bq_a[h * 32 + d] * R_wb[(h * 32 + d) * 32 + fd];
            v = s;
        }
        bcat_a[c] = v;
    }
}

// ---------------------------------------------------------------------------
// Kernel 1b: Wo transposed to bf16: Wto[c][k] = Wo[k][c].
// ---------------------------------------------------------------------------
__global__ __launch_bounds__(256) void prep_wo(
    const float* __restrict__ Wo_p, const float* __restrict__ Wo_a,
    unsigned short* __restrict__ Wto_p, unsigned short* __restrict__ Wto_a)
{
    int tid = blockIdx.x * 256 + threadIdx.x;   // 0..131071
    int which = tid >> 16, i = tid & 65535;
    int c = i >> 8, k = i & 255;
    const float* W = which ? Wo_a : Wo_p;
    unsigned short* o = which ? Wto_a : Wto_p;
    o[i] = f2bf(W[k * 256 + c]);
}

// ---------------------------------------------------------------------------
// Kernel 2: MFMA GEMM, bf16 in / bf16 out.  Y = Xb @ Wt^T + bias.
// 128x128 tile, 4 waves 2x2, BK=64. Staging via global_load_lds width=16 into
// LINEAR LDS [128][64]; XOR-swizzle (slot ^= row&7, 16B slots) applied to the
// GLOBAL source and to the ds_read_b128 fragment address (rule 21: both-sides).
// Grid is 1-D with the m204 bijective XCD-chunk swizzle so the col-blocks of a
// row-tile co-reside on one XCD (A-tile L2 reuse).
// ---------------------------------------------------------------------------
__global__ __launch_bounds__(256) void gemm_mfma(
    const unsigned short* __restrict__ Xb, const unsigned short* __restrict__ Wt,
    const float* __restrict__ bias, unsigned short* __restrict__ Y,
    int nrows, int ncols)
{
    __shared__ unsigned short As[128 * 64];
    __shared__ unsigned short Bs[128 * 64];
    const int t = threadIdx.x;
    const int wave = t >> 6, lane = t & 63;
    const int wm = wave >> 1, wn = wave & 1;
    const int lquad = lane >> 4, lmod = lane & 15;

    // m204 bijective XCD swizzle
    const unsigned nwg = gridDim.x, orig = blockIdx.x;
    const unsigned q = nwg >> 3, rr8 = nwg & 7, xcd = orig & 7, lo = orig >> 3;
    const unsigned wg = (xcd < rr8 ? xcd * (q + 1) : rr8 * (q + 1) + (xcd - rr8) * q) + lo;
    const int cb = ncols >> 7;
    const int cx = wg % cb, ry = wg / cb;
    const int row0 = ry * 128, col0 = cx * 128;

    // staging geometry: pass covers 8 rows (8 x 128B = 1KB); lane l -> row +l>>3,
    // physical 16B slot l&7; global slot = (l&7) ^ (l>>3).
    const int sr = lane >> 3;                 // 0..7 (also row&7 within a pass)
    const int sslot = (lane & 7) ^ sr;        // swizzled source slot
    const int lrow = nrows - 1;

    f32x4 acc[4][4];
    #pragma unroll
    for (int i = 0; i < 4; i++)
        #pragma unroll
        for (int j = 0; j < 4; j++) acc[i][j] = (f32x4){0.f, 0.f, 0.f, 0.f};

    for (int k0 = 0; k0 < 256; k0 += 64) {
        // stage A: rows row0 .. row0+127 (clamped), 64 bf16 each
        #pragma unroll
        for (int pp = 0; pp < 4; pp++) {
            const int pass = wave * 4 + pp;
            const int r = pass * 8 + sr;
            int gr = row0 + r; if (gr > lrow) gr = lrow;
            gload_lds16(&Xb[(size_t)gr * 256 + k0 + sslot * 8], &As[r * 64 + (lane & 7) * 8]);
        }
        // stage B: Wt rows col0 .. col0+127
        #pragma unroll
        for (int pp = 0; pp < 4; pp++) {
            const int pass = wave * 4 + pp;
            const int r = pass * 8 + sr;
            gload_lds16(&Wt[(size_t)(col0 + r) * 256 + k0 + sslot * 8], &Bs[r * 64 + (lane & 7) * 8]);
        }
        __syncthreads();   // drains vmcnt -> LDS tiles ready
        #pragma unroll
        for (int ks = 0; ks < 2; ks++) {
            bf16x8 af[4], bfr[4];
            #pragma unroll
            for (int i = 0; i < 4; i++) {
                const int ar = wm * 64 + i * 16 + lmod;
                af[i] = *(const bf16x8*)&As[ar * 64 + (((ks * 4 + lquad) ^ (ar & 7)) << 3)];
            }
            #pragma unroll
            for (int j = 0; j < 4; j++) {
                const int br = wn * 64 + j * 16 + lmod;
                bfr[j] = *(const bf16x8*)&Bs[br * 64 + (((ks * 4 + lquad) ^ (br & 7)) << 3)];
            }
            #pragma unroll
            for (int i = 0; i < 4; i++)
                #pragma unroll
                for (int j = 0; j < 4; j++)
                    acc[i][j] = __builtin_amdgcn_mfma_f32_16x16x32_bf16(af[i], bfr[j], acc[i][j], 0, 0, 0);
        }
        __syncthreads();   // safe to overwrite LDS next iteration
    }

    // C/D layout: col = lane&15, row = (lane>>4)*4 + reg  (m89-verified)
    float bj[4];
    #pragma unroll
    for (int j = 0; j < 4; j++) bj[j] = bias[col0 + wn * 64 + j * 16 + lmod];
    #pragma unroll
    for (int i = 0; i < 4; i++) {
        int rbase = row0 + wm * 64 + i * 16 + lquad * 4;
        #pragma unroll
        for (int rg = 0; rg < 4; rg++) {
            int r = rbase + rg;
            if (r < nrows) {
                #pragma unroll
                for (int j = 0; j < 4; j++) {
                    int c = col0 + wn * 64 + j * 16 + lmod;
                    Y[(size_t)r * ncols + c] = f2bf(acc[i][j][rg] + bj[j]);
                }
            }
        }
    }
}

// ---------------------------------------------------------------------------
// CSR build (unchanged).
// ---------------------------------------------------------------------------
__global__ __launch_bounds__(256) void hist_kernel(const int* __restrict__ ei, int E,
                                                   int* __restrict__ cnt)
{
    int i = blockIdx.x * 256 + threadIdx.x;
    if (i < E) atomicAdd(&cnt[ei[E + i]], 1);
}

__global__ __launch_bounds__(256) void scan1(const int* __restrict__ cnt, int n,
                                             int* __restrict__ bsum)
{
    __shared__ int s[256];
    int b = blockIdx.x, t = threadIdx.x;
    int i0 = b * 1024 + t * 4, v = 0;
    if (i0 + 3 < n) {
        int4 q = *(const int4*)&cnt[i0];
        v = q.x + q.y + q.z + q.w;
    } else {
        for (int j = 0; j < 4; j++) if (i0 + j < n) v += cnt[i0 + j];
    }
    s[t] = v; __syncthreads();
    for (int off = 128; off > 0; off >>= 1) {
        if (t < off) s[t] += s[t + off];
        __syncthreads();
    }
    if (t == 0) bsum[b] = s[0];
}

__global__ __launch_bounds__(256) void scan2(int* __restrict__ bsum, int nb)
{
    __shared__ int s[256];
    int t = threadIdx.x;
    int v = (t < nb) ? bsum[t] : 0;
    s[t] = v; __syncthreads();
    for (int off = 1; off < 256; off <<= 1) {
        int x = 0;
        if (t >= off) x = s[t - off];
        __syncthreads();
        s[t] += x;
        __syncthreads();
    }
    if (t < nb) bsum[t] = s[t] - v;   // exclusive
}

__global__ __launch_bounds__(256) void scan3(int* __restrict__ cnt, int n,
                                             const int* __restrict__ bsum,
                                             int* __restrict__ row_ptr)
{
    __shared__ int s[256];
    int b = blockIdx.x, t = threadIdx.x;
    int i0 = b * 1024 + t * 4;
    int v[4]; int tot = 0;
    #pragma unroll
    for (int j = 0; j < 4; j++) { v[j] = (i0 + j < n) ? cnt[i0 + j] : 0; tot += v[j]; }
    s[t] = tot; __syncthreads();
    for (int off = 1; off < 256; off <<= 1) {
        int x = 0;
        if (t >= off) x = s[t - off];
        __syncthreads();
        s[t] += x;
        __syncthreads();
    }
    int run = s[t] - tot + bsum[b];
    #pragma unroll
    for (int j = 0; j < 4; j++) {
        int i = i0 + j;
        if (i < n) {
            row_ptr[i] = run;
            cnt[i] = run;      // cursor
            run += v[j];
            if (i == n - 1) row_ptr[n] = run;
        }
    }
}

__global__ __launch_bounds__(256) void scatter_kernel(const int* __restrict__ ei, int E, int rel,
                                                      int* __restrict__ cursor, int* __restrict__ eout)
{
    int i = blockIdx.x * 256 + threadIdx.x;
    if (i < E) {
        int pos = atomicAdd(&cursor[ei[E + i]], 1);
        eout[pos] = (ei[i] << 1) | rel;
    }
}

// ---------------------------------------------------------------------------
// Kernel 3: per-node gather-reduce; fuses the /norm division, writes agg f32.
// ---------------------------------------------------------------------------
__global__ __launch_bounds__(256) void aggregate_kernel(
    const unsigned short* __restrict__ Ydst, int dstride, int qoff0, int qoff1,
    const unsigned short* __restrict__ Ysrc0, int sstride0,
    const unsigned short* __restrict__ Ysrc1, int sstride1,
    const int* __restrict__ row_ptr, const int* __restrict__ edges,
    int nnodes, float* __restrict__ agg)
{
    const int wave = threadIdx.x >> 6, lane = threadIdx.x & 63;
    const int node = blockIdx.x * 4 + wave;
    if (node >= nnodes) return;

    const ushort4 q0u = *(const ushort4*)&Ydst[(size_t)node * dstride + qoff0 + lane * 4];
    const ushort4 q1u = *(const ushort4*)&Ydst[(size_t)node * dstride + qoff1 + lane * 4];
    const float q0x = bf2f(q0u.x), q0y = bf2f(q0u.y), q0z = bf2f(q0u.z), q0w = bf2f(q0u.w);
    const float q1x = bf2f(q1u.x), q1y = bf2f(q1u.y), q1z = bf2f(q1u.z), q1w = bf2f(q1u.w);

    float a0 = 0.f, a1 = 0.f, a2 = 0.f, a3 = 0.f, hs = 0.f;
    const int beg = row_ptr[node], end = row_ptr[node + 1];
    for (int i = beg; i < end; i++) {
        const int e = edges[i];
        const int rel = e & 1;
        const size_t src = (size_t)(e >> 1);
        const unsigned short* Ys = rel ? Ysrc1 : Ysrc0;
        const int ss = rel ? sstride1 : sstride0;
        const ushort4 ku = *(const ushort4*)&Ys[src * ss + lane * 4];
        const ushort4 vu = *(const ushort4*)&Ys[src * ss + 256 + lane * 4];
        float p = (rel ? q1x : q0x) * bf2f(ku.x) + (rel ? q1y : q0y) * bf2f(ku.y)
                + (rel ? q1z : q0z) * bf2f(ku.z) + (rel ? q1w : q0w) * bf2f(ku.w);
        p += __shfl_xor(p, 1);
        p += __shfl_xor(p, 2);
        p += __shfl_xor(p, 4);
        float sc = fminf(fmaxf(p * RSCALE, -5.f), 5.f);
        float a = expf(sc);
        a0 += bf2f(vu.x) * a;
        a1 += bf2f(vu.y) * a;
        a2 += bf2f(vu.z) * a;
        a3 += bf2f(vu.w) * a;
        hs += a;
    }
    hs += __shfl_xor(hs, 8);
    hs += __shfl_xor(hs, 16);
    hs += __shfl_xor(hs, 32);

    const float inv = 1.f / fmaxf(hs * 0.125f, 1e-8f);
    float4 o = make_float4(a0 * inv, a1 * inv, a2 * inv, a3 * inv);
    *(float4*)&agg[(size_t)node * 256 + lane * 4] = o;
}

// ---------------------------------------------------------------------------
// Kernel 4: fused output projection + residual + LayerNorm on MFMA (unchanged).
// ---------------------------------------------------------------------------
__global__ __launch_bounds__(256) void ogemm_ln_kernel(
    const float* agg,                         // [nrows][256] f32 (aliases out)
    const unsigned short* __restrict__ Wt,    // [256][256] bf16, row = out col
    const float* __restrict__ bo, const float* __restrict__ x,
    const float* __restrict__ g, const float* __restrict__ be,
    float* out, int nrows)
{
    __shared__ __align__(16) char smem[64 * 264 * 4];   // 67.6 KB -> 2 blocks/CU
    unsigned short* As_hi = (unsigned short*)smem;      // [64][72]
    unsigned short* As_lo = As_hi + 64 * 72;            // [64][72]
    unsigned short* Bs    = As_lo + 64 * 72;            // [256][72]
    float* Yo = (float*)smem;                           // [64][264] (reused)

    const int t = threadIdx.x;
    const int wave = t >> 6, lane = t & 63;
    const int lquad = lane >> 4, lmod = lane & 15;
    const int row0 = blockIdx.x * 64;
    const int wcol = wave * 64;

    f32x4 acc[4][4];
    #pragma unroll
    for (int i = 0; i < 4; i++)
        #pragma unroll
        for (int j = 0; j < 4; j++) acc[i][j] = (f32x4){0.f, 0.f, 0.f, 0.f};

    for (int k0 = 0; k0 < 256; k0 += 64) {
        #pragma unroll
        for (int p = 0; p < 2; p++) {
            int r = p * 32 + (t >> 3);
            int c8 = (t & 7) * 8;
            float4 v0 = make_float4(0.f, 0.f, 0.f, 0.f), v1 = v0;
            if (row0 + r < nrows) {
                v0 = *(const float4*)&agg[(size_t)(row0 + r) * 256 + k0 + c8];
                v1 = *(const float4*)&agg[(size_t)(row0 + r) * 256 + k0 + c8 + 4];
            }
            ushort4 h0, h1, l0, l1;
            h0.x = f2bf(v0.x); l0.x = f2bf(v0.x - bf2f(h0.x));
            h0.y = f2bf(v0.y); l0.y = f2bf(v0.y - bf2f(h0.y));
            h0.z = f2bf(v0.z); l0.z = f2bf(v0.z - bf2f(h0.z));
            h0.w = f2bf(v0.w); l0.w = f2bf(v0.w - bf2f(h0.w));
            h1.x = f2bf(v1.x); l1.x = f2bf(v1.x - bf2f(h1.x));
            h1.y = f2bf(v1.y); l1.y = f2bf(v1.y - bf2f(h1.y));
            h1.z = f2bf(v1.z); l1.z = f2bf(v1.z - bf2f(h1.z));
            h1.w = f2bf(v1.w); l1.w = f2bf(v1.w - bf2f(h1.w));
            *(ushort4*)&As_hi[r * 72 + c8]     = h0;
            *(ushort4*)&As_hi[r * 72 + c8 + 4] = h1;
            *(ushort4*)&As_lo[r * 72 + c8]     = l0;
            *(ushort4*)&As_lo[r * 72 + c8 + 4] = l1;
        }
        #pragma unroll
        for (int p = 0; p < 8; p++) {
            int r = p * 32 + (t >> 3);
            int c8 = (t & 7) * 8;
            *(float4*)&Bs[r * 72 + c8] = *(const float4*)&Wt[(size_t)r * 256 + k0 + c8];
        }
        __syncthreads();
        #pragma unroll
        for (int ks = 0; ks < 2; ks++) {
            bf16x8 ah[4], al[4], bfr[4];
            #pragma unroll
            for (int i = 0; i < 4; i++) {
                ah[i] = *(const bf16x8*)&As_hi[(i * 16 + lmod) * 72 + ks * 32 + lquad * 8];
                al[i] = *(const bf16x8*)&As_lo[(i * 16 + lmod) * 72 + ks * 32 + lquad * 8];
            }
            #pragma unroll
            for (int j = 0; j < 4; j++)
                bfr[j] = *(const bf16x8*)&Bs[(wcol + j * 16 + lmod) * 72 + ks * 32 + lquad * 8];
            #pragma unroll
            for (int i = 0; i < 4; i++)
                #pragma unroll
                for (int j = 0; j < 4; j++) {
                    acc[i][j] = __builtin_amdgcn_mfma_f32_16x16x32_bf16(ah[i], bfr[j], acc[i][j], 0, 0, 0);
                    acc[i][j] = __builtin_amdgcn_mfma_f32_16x16x32_bf16(al[i], bfr[j], acc[i][j], 0, 0, 0);
                }
        }
        __syncthreads();
    }

    float bj[4];
    #pragma unroll
    for (int j = 0; j < 4; j++) bj[j] = bo[wcol + j * 16 + lmod];
    #pragma unroll
    for (int i = 0; i < 4; i++)
        #pragma unroll
        for (int j = 0; j < 4; j++)
            #pragma unroll
            for (int rg = 0; rg < 4; rg++)
                Yo[(i * 16 + lquad * 4 + rg) * 264 + wcol + j * 16 + lmod] = acc[i][j][rg] + bj[j];
    __syncthreads();

    const float4 gv  = *(const float4*)&g[lane * 4];
    const float4 bev = *(const float4*)&be[lane * 4];
    #pragma unroll 1
    for (int ii = 0; ii < 16; ii++) {
        int lr = wave * 16 + ii;
        int r = row0 + lr;
        if (r >= nrows) break;
        float4 y = *(const float4*)&Yo[lr * 264 + lane * 4];
        float4 xv = *(const float4*)&x[(size_t)r * 256 + lane * 4];
        y.x += xv.x; y.y += xv.y; y.z += xv.z; y.w += xv.w;
        float sum = y.x + y.y + y.z + y.w;
        for (int o = 1; o < 64; o <<= 1) sum += __shfl_xor(sum, o);
        float m = sum * (1.f / 256.f);
        float d0 = y.x - m, d1 = y.y - m, d2 = y.z - m, d3 = y.w - m;
        float vs = d0 * d0 + d1 * d1 + d2 * d2 + d3 * d3;
        for (int o = 1; o < 64; o <<= 1) vs += __shfl_xor(vs, o);
        float rstd = rsqrtf(vs * (1.f / 256.f) + 1e-5f);
        float4 o4;
        o4.x = d0 * rstd * gv.x + bev.x;
        o4.y = d1 * rstd * gv.y + bev.y;
        o4.z = d2 * rstd * gv.z + bev.z;
        o4.w = d3 * rstd * gv.w + bev.w;
        *(float4*)&out[(size_t)r * 256 + lane * 4] = o4;
    }
}

// ---------------------------------------------------------------------------
extern "C" void kernel_launch(void* const* d_in, const int* in_sizes, int n_in,
                              void* d_out, int out_size, void* d_ws, size_t ws_size,
                              hipStream_t stream)
{
    const float* x_p  = (const float*)d_in[0];
    const float* x_a  = (const float*)d_in[1];
    const float* Wk_p = (const float*)d_in[2];
    const float* bk_p = (const float*)d_in[3];
    const float* Wq_p = (const float*)d_in[4];
    const float* bq_p = (const float*)d_in[5];
    const float* Wv_p = (const float*)d_in[6];
    const float* bv_p = (const float*)d_in[7];
    const float* Wo_p = (const float*)d_in[8];
    const float* bo_p = (const float*)d_in[9];
    const float* g_p  = (const float*)d_in[10];
    const float* be_p = (const float*)d_in[11];
    const float* Wk_a = (const float*)d_in[12];
    const float* bk_a = (const float*)d_in[13];
    const float* Wq_a = (const float*)d_in[14];
    const float* bq_a = (const float*)d_in[15];
    const float* Wv_a = (const float*)d_in[16];
    const float* bv_a = (const float*)d_in[17];
    const float* Wo_a = (const float*)d_in[18];
    const float* bo_a = (const float*)d_in[19];
    const float* g_a  = (const float*)d_in[20];
    const float* be_a = (const float*)d_in[21];
    const float* R_w  = (const float*)d_in[22];
    const int*   ei_w = (const int*)d_in[23];
    const float* R_c  = (const float*)d_in[24];
    const int*   ei_c = (const int*)d_in[25];
    const float* R_wb = (const float*)d_in[26];
    const int*   ei_wb= (const int*)d_in[27];

    const int N   = in_sizes[0] / 256;
    const int Ew  = in_sizes[23] / 2;
    const int Ec  = in_sizes[25] / 2;
    const int Ewb = in_sizes[27] / 2;

    size_t off = 0;
    auto walloc = [&](size_t bytes) {
        void* p = (char*)d_ws + off;
        off += (bytes + 255) & ~(size_t)255;
        return p;
    };
    unsigned short* Xb_p = (unsigned short*)walloc((size_t)N * 256 * 2);
    unsigned short* Xb_a = (unsigned short*)walloc((size_t)N * 256 * 2);
    unsigned short* Wt_p = (unsigned short*)walloc((size_t)1024 * 256 * 2);
    unsigned short* Wt_a = (unsigned short*)walloc((size_t)768 * 256 * 2);
    unsigned short* Wto_p = (unsigned short*)walloc((size_t)256 * 256 * 2);
    unsigned short* Wto_a = (unsigned short*)walloc((size_t)256 * 256 * 2);
    float* bcat_p = (float*)walloc(1024 * 4);
    float* bcat_a = (float*)walloc(768 * 4);
    unsigned short* Y_p = (unsigned short*)walloc((size_t)N * 1024 * 2);
    unsigned short* Y_a = (unsigned short*)walloc((size_t)N * 768 * 2);
    int* cnt_p = (int*)walloc((size_t)N * 4);        // histogram -> cursor
    int* rp_p  = (int*)walloc((size_t)(N + 1) * 4);
    int* e_p   = (int*)walloc((size_t)(Ew + Ec) * 4);
    int* cnt_a = (int*)walloc((size_t)N * 4);
    int* rp_a  = (int*)walloc((size_t)(N + 1) * 4);
    int* e_a   = (int*)walloc((size_t)Ewb * 4);
    int* bsum  = (int*)walloc(1024 * 4);

    float* agg_p = (float*)d_out;
    float* agg_a = (float*)d_out + (size_t)N * 256;

    const int nb = (N + 1023) / 1024;   // scan blocks (98 for N=100k)

    hipMemsetAsync(cnt_p, 0, (size_t)N * 4, stream);
    hipMemsetAsync(cnt_a, 0, (size_t)N * 4, stream);

    {
        int total = 1024 * 256 + 768 * 256 + 1024 + 768;
        prep_weights<<<(total + 255) / 256, 256, 0, stream>>>(
            Wk_p, Wv_p, Wq_p, R_w, R_c, bk_p, bv_p, bq_p,
            Wk_a, Wv_a, Wq_a, R_wb, bk_a, bv_a, bq_a,
            Wt_p, bcat_p, Wt_a, bcat_a);
        prep_wo<<<(2 * 256 * 256) / 256, 256, 0, stream>>>(Wo_p, Wo_a, Wto_p, Wto_a);
        convert_bf16<<<2048, 256, 0, stream>>>(x_p, x_a, Xb_p, Xb_a, N * 32);
    }

    // histograms (independent of GEMMs)
    hist_kernel<<<(Ew + 255) / 256, 256, 0, stream>>>(ei_w, Ew, cnt_p);
    hist_kernel<<<(Ec + 255) / 256, 256, 0, stream>>>(ei_c, Ec, cnt_p);
    hist_kernel<<<(Ewb + 255) / 256, 256, 0, stream>>>(ei_wb, Ewb, cnt_a);

    // projections (MFMA)
    {
        int rb = (N + 127) / 128;
        gemm_mfma<<<8 * rb, 256, 0, stream>>>(Xb_p, Wt_p, bcat_p, Y_p, N, 1024);
        gemm_mfma<<<6 * rb, 256, 0, stream>>>(Xb_a, Wt_a, bcat_a, Y_a, N, 768);
    }

    // CSR: papers
    scan1<<<nb, 256, 0, stream>>>(cnt_p, N, bsum);
    scan2<<<1, 256, 0, stream>>>(bsum, nb);
    scan3<<<nb, 256, 0, stream>>>(cnt_p, N, bsum, rp_p);
    scatter_kernel<<<(Ew + 255) / 256, 256, 0, stream>>>(ei_w, Ew, 0, cnt_p, e_p);
    scatter_kernel<<<(Ec + 255) / 256, 256, 0, stream>>>(ei_c, Ec, 1, cnt_p, e_p);
    // CSR: authors
    scan1<<<nb, 256, 0, stream>>>(cnt_a, N, bsum);
    scan2<<<1, 256, 0, stream>>>(bsum, nb);
    scan3<<<nb, 256, 0, stream>>>(cnt_a, N, bsum, rp_a);
    scatter_kernel<<<(Ewb + 255) / 256, 256, 0, stream>>>(ei_wb, Ewb, 0, cnt_a, e_a);

    // aggregate: papers receive writes(rel0, src=author) + cites(rel1, src=paper)
    aggregate_kernel<<<(N + 3) / 4, 256, 0, stream>>>(
        Y_p, 1024, 512, 768, Y_a, 768, Y_p, 1024, rp_p, e_p, N, agg_p);
    // authors receive writtenby(rel0, src=paper); Q at col 512 of Y_a
    aggregate_kernel<<<(N + 3) / 4, 256, 0, stream>>>(
        Y_a, 768, 512, 512, Y_p, 1024, Y_p, 1024, rp_a, e_a, N, agg_a);

    // fused output projection + residual + LayerNorm (in-place over agg)
    ogemm_ln_kernel<<<(N + 63) / 64, 256, 0, stream>>>(agg_p, Wto_p, bo_p, x_p, g_p, be_p, agg_p, N);
    ogemm_ln_kernel<<<(N + 63) / 64, 256, 0, stream>>>(agg_a, Wto_a, bo_a, x_a, g_a, be_a, agg_a, N);
}

// Round 3
// 1130.887 us; speedup vs baseline: 1.6010x; 1.0405x over previous
//
#include <hip/hip_runtime.h>

#define RSCALE 0.17677669529663687f   // 1/sqrt(32)

typedef __attribute__((ext_vector_type(8))) short bf16x8;
typedef __attribute__((ext_vector_type(8))) unsigned short u16x8;
typedef __attribute__((ext_vector_type(4))) float f32x4;

__device__ __forceinline__ float bf2f(unsigned short u) {
    return __uint_as_float(((unsigned)u) << 16);
}
__device__ __forceinline__ unsigned short f2bf(float f) {
    unsigned u = __float_as_uint(f);
    u += 0x7FFFu + ((u >> 16) & 1u);   // round-to-nearest-even
    return (unsigned short)(u >> 16);
}

// direct global->LDS async copy, 16 B per lane.
__device__ __forceinline__ void gload_lds16(const unsigned short* g, unsigned short* l) {
    __builtin_amdgcn_global_load_lds(
        (const __attribute__((address_space(1))) void*)g,
        (__attribute__((address_space(3))) void*)l, 16, 0, 0);
}

// ---------------------------------------------------------------------------
// Kernel 0: x (f32) -> bf16 once.
// ---------------------------------------------------------------------------
__global__ __launch_bounds__(256) void convert_bf16(
    const float* __restrict__ xp, const float* __restrict__ xa,
    unsigned short* __restrict__ bp, unsigned short* __restrict__ ba, int nper)  // nper = N*256/8
{
    const int stride = gridDim.x * 256;
    for (int i = blockIdx.x * 256 + threadIdx.x; i < 2 * nper; i += stride) {
        const float* src = (i < nper) ? xp : xa;
        unsigned short* dst = (i < nper) ? bp : ba;
        const int j = (i < nper) ? i : i - nper;
        float4 v0 = *(const float4*)&src[(size_t)j * 8];
        float4 v1 = *(const float4*)&src[(size_t)j * 8 + 4];
        u16x8 o;
        o[0] = f2bf(v0.x); o[1] = f2bf(v0.y); o[2] = f2bf(v0.z); o[3] = f2bf(v0.w);
        o[4] = f2bf(v1.x); o[5] = f2bf(v1.y); o[6] = f2bf(v1.z); o[7] = f2bf(v1.w);
        *(u16x8*)&dst[(size_t)j * 8] = o;
    }
}

// ---------------------------------------------------------------------------
// Kernel 1: fused weights, TRANSPOSED + bf16 for the MFMA GEMM.
// ---------------------------------------------------------------------------
__global__ __launch_bounds__(256) void prep_weights(
    const float* __restrict__ Wk_p, const float* __restrict__ Wv_p, const float* __restrict__ Wq_p,
    const float* __restrict__ R_w,  const float* __restrict__ R_c,
    const float* __restrict__ bk_p, const float* __restrict__ bv_p, const float* __restrict__ bq_p,
    const float* __restrict__ Wk_a, const float* __restrict__ Wv_a, const float* __restrict__ Wq_a,
    const float* __restrict__ R_wb,
    const float* __restrict__ bk_a, const float* __restrict__ bv_a, const float* __restrict__ bq_a,
    unsigned short* __restrict__ Wt_p, float* __restrict__ bcat_p,
    unsigned short* __restrict__ Wt_a, float* __restrict__ bcat_a)
{
    const int WP = 1024 * 256, WA = 768 * 256;
    int tid = blockIdx.x * 256 + threadIdx.x;
    if (tid < WP) {
        int c = tid >> 8, k = tid & 255;
        float v;
        if (c < 256)       v = Wk_p[k * 256 + c];
        else if (c < 512)  v = Wv_p[k * 256 + (c - 256)];
        else {
            int f = c & 255;
            const float* R = (c < 768) ? R_w : R_c;
            int h = f >> 5, fd = f & 31;
            float s = 0.f;
            #pragma unroll
            for (int d = 0; d < 32; d++) s += Wq_p[k * 256 + h * 32 + d] * R[(h * 32 + d) * 32 + fd];
            v = s;
        }
        Wt_p[tid] = f2bf(v);
    } else if (tid < WP + WA) {
        int t2 = tid - WP;
        int c = t2 >> 8, k = t2 & 255;
        float v;
        if (c < 256)       v = Wk_a[k * 256 + c];
        else if (c < 512)  v = Wv_a[k * 256 + (c - 256)];
        else {
            int f = c - 512, h = f >> 5, fd = f & 31;
            float s = 0.f;
            #pragma unroll
            for (int d = 0; d < 32; d++) s += Wq_a[k * 256 + h * 32 + d] * R_wb[(h * 32 + d) * 32 + fd];
            v = s;
        }
        Wt_a[t2] = f2bf(v);
    } else if (tid < WP + WA + 1024) {
        int c = tid - WP - WA;
        float v;
        if (c < 256)       v = bk_p[c];
        else if (c < 512)  v = bv_p[c - 256];
        else {
            int f = c & 255;
            const float* R = (c < 768) ? R_w : R_c;
            int h = f >> 5, fd = f & 31;
            float s = 0.f;
            #pragma unroll
            for (int d = 0; d < 32; d++) s += bq_p[h * 32 + d] * R[(h * 32 + d) * 32 + fd];
            v = s;
        }
        bcat_p[c] = v;
    } else if (tid < WP + WA + 1024 + 768) {
        int c = tid - WP - WA - 1024;
        float v;
        if (c < 256)       v = bk_a[c];
        else if (c < 512)  v = bv_a[c - 256];
        else {
            int f = c - 512, h = f >> 5, fd = f & 31;
            float s = 0.f;
            #pragma unroll
            for (int d = 0; d < 32; d++) s += bq_a[h * 32 + d] * R_wb[(h * 32 + d) * 32 + fd];
            v = s;
        }
        bcat_a[c] = v;
    }
}

// ---------------------------------------------------------------------------
// Kernel 1b: Wo transposed to bf16: Wto[c][k] = Wo[k][c].
// ---------------------------------------------------------------------------
__global__ __launch_bounds__(256) void prep_wo(
    const float* __restrict__ Wo_p, const float* __restrict__ Wo_a,
    unsigned short* __restrict__ Wto_p, unsigned short* __restrict__ Wto_a)
{
    int tid = blockIdx.x * 256 + threadIdx.x;   // 0..131071
    int which = tid >> 16, i = tid & 65535;
    int c = i >> 8, k = i & 255;
    const float* W = which ? Wo_a : Wo_p;
    unsigned short* o = which ? Wto_a : Wto_p;
    o[i] = f2bf(W[k * 256 + c]);
}

// ---------------------------------------------------------------------------
// Kernel 2: MFMA GEMM, bf16 in / bf16 out.  Y = Xb @ Wt^T + bias.
// (unchanged from round 2: gload_lds + XOR swizzle + XCD-chunk grid)
// ---------------------------------------------------------------------------
__global__ __launch_bounds__(256) void gemm_mfma(
    const unsigned short* __restrict__ Xb, const unsigned short* __restrict__ Wt,
    const float* __restrict__ bias, unsigned short* __restrict__ Y,
    int nrows, int ncols)
{
    __shared__ unsigned short As[128 * 64];
    __shared__ unsigned short Bs[128 * 64];
    const int t = threadIdx.x;
    const int wave = t >> 6, lane = t & 63;
    const int wm = wave >> 1, wn = wave & 1;
    const int lquad = lane >> 4, lmod = lane & 15;

    const unsigned nwg = gridDim.x, orig = blockIdx.x;
    const unsigned q = nwg >> 3, rr8 = nwg & 7, xcd = orig & 7, lo = orig >> 3;
    const unsigned wg = (xcd < rr8 ? xcd * (q + 1) : rr8 * (q + 1) + (xcd - rr8) * q) + lo;
    const int cb = ncols >> 7;
    const int cx = wg % cb, ry = wg / cb;
    const int row0 = ry * 128, col0 = cx * 128;

    const int sr = lane >> 3;                 // 0..7
    const int sslot = (lane & 7) ^ sr;        // swizzled source slot
    const int lrow = nrows - 1;

    f32x4 acc[4][4];
    #pragma unroll
    for (int i = 0; i < 4; i++)
        #pragma unroll
        for (int j = 0; j < 4; j++) acc[i][j] = (f32x4){0.f, 0.f, 0.f, 0.f};

    for (int k0 = 0; k0 < 256; k0 += 64) {
        #pragma unroll
        for (int pp = 0; pp < 4; pp++) {
            const int pass = wave * 4 + pp;
            const int r = pass * 8 + sr;
            int gr = row0 + r; if (gr > lrow) gr = lrow;
            gload_lds16(&Xb[(size_t)gr * 256 + k0 + sslot * 8], &As[r * 64 + (lane & 7) * 8]);
        }
        #pragma unroll
        for (int pp = 0; pp < 4; pp++) {
            const int pass = wave * 4 + pp;
            const int r = pass * 8 + sr;
            gload_lds16(&Wt[(size_t)(col0 + r) * 256 + k0 + sslot * 8], &Bs[r * 64 + (lane & 7) * 8]);
        }
        __syncthreads();
        #pragma unroll
        for (int ks = 0; ks < 2; ks++) {
            bf16x8 af[4], bfr[4];
            #pragma unroll
            for (int i = 0; i < 4; i++) {
                const int ar = wm * 64 + i * 16 + lmod;
                af[i] = *(const bf16x8*)&As[ar * 64 + (((ks * 4 + lquad) ^ (ar & 7)) << 3)];
            }
            #pragma unroll
            for (int j = 0; j < 4; j++) {
                const int br = wn * 64 + j * 16 + lmod;
                bfr[j] = *(const bf16x8*)&Bs[br * 64 + (((ks * 4 + lquad) ^ (br & 7)) << 3)];
            }
            #pragma unroll
            for (int i = 0; i < 4; i++)
                #pragma unroll
                for (int j = 0; j < 4; j++)
                    acc[i][j] = __builtin_amdgcn_mfma_f32_16x16x32_bf16(af[i], bfr[j], acc[i][j], 0, 0, 0);
        }
        __syncthreads();
    }

    float bj[4];
    #pragma unroll
    for (int j = 0; j < 4; j++) bj[j] = bias[col0 + wn * 64 + j * 16 + lmod];
    #pragma unroll
    for (int i = 0; i < 4; i++) {
        int rbase = row0 + wm * 64 + i * 16 + lquad * 4;
        #pragma unroll
        for (int rg = 0; rg < 4; rg++) {
            int r = rbase + rg;
            if (r < nrows) {
                #pragma unroll
                for (int j = 0; j < 4; j++) {
                    int c = col0 + wn * 64 + j * 16 + lmod;
                    Y[(size_t)r * ncols + c] = f2bf(acc[i][j][rg] + bj[j]);
                }
            }
        }
    }
}

// ---------------------------------------------------------------------------
// CSR build (unchanged).
// ---------------------------------------------------------------------------
__global__ __launch_bounds__(256) void hist_kernel(const int* __restrict__ ei, int E,
                                                   int* __restrict__ cnt)
{
    int i = blockIdx.x * 256 + threadIdx.x;
    if (i < E) atomicAdd(&cnt[ei[E + i]], 1);
}

__global__ __launch_bounds__(256) void scan1(const int* __restrict__ cnt, int n,
                                             int* __restrict__ bsum)
{
    __shared__ int s[256];
    int b = blockIdx.x, t = threadIdx.x;
    int i0 = b * 1024 + t * 4, v = 0;
    if (i0 + 3 < n) {
        int4 q = *(const int4*)&cnt[i0];
        v = q.x + q.y + q.z + q.w;
    } else {
        for (int j = 0; j < 4; j++) if (i0 + j < n) v += cnt[i0 + j];
    }
    s[t] = v; __syncthreads();
    for (int off = 128; off > 0; off >>= 1) {
        if (t < off) s[t] += s[t + off];
        __syncthreads();
    }
    if (t == 0) bsum[b] = s[0];
}

__global__ __launch_bounds__(256) void scan2(int* __restrict__ bsum, int nb)
{
    __shared__ int s[256];
    int t = threadIdx.x;
    int v = (t < nb) ? bsum[t] : 0;
    s[t] = v; __syncthreads();
    for (int off = 1; off < 256; off <<= 1) {
        int x = 0;
        if (t >= off) x = s[t - off];
        __syncthreads();
        s[t] += x;
        __syncthreads();
    }
    if (t < nb) bsum[t] = s[t] - v;   // exclusive
}

__global__ __launch_bounds__(256) void scan3(int* __restrict__ cnt, int n,
                                             const int* __restrict__ bsum,
                                             int* __restrict__ row_ptr)
{
    __shared__ int s[256];
    int b = blockIdx.x, t = threadIdx.x;
    int i0 = b * 1024 + t * 4;
    int v[4]; int tot = 0;
    #pragma unroll
    for (int j = 0; j < 4; j++) { v[j] = (i0 + j < n) ? cnt[i0 + j] : 0; tot += v[j]; }
    s[t] = tot; __syncthreads();
    for (int off = 1; off < 256; off <<= 1) {
        int x = 0;
        if (t >= off) x = s[t - off];
        __syncthreads();
        s[t] += x;
        __syncthreads();
    }
    int run = s[t] - tot + bsum[b];
    #pragma unroll
    for (int j = 0; j < 4; j++) {
        int i = i0 + j;
        if (i < n) {
            row_ptr[i] = run;
            cnt[i] = run;      // cursor
            run += v[j];
            if (i == n - 1) row_ptr[n] = run;
        }
    }
}

__global__ __launch_bounds__(256) void scatter_kernel(const int* __restrict__ ei, int E, int rel,
                                                      int* __restrict__ cursor, int* __restrict__ eout)
{
    int i = blockIdx.x * 256 + threadIdx.x;
    if (i < E) {
        int pos = atomicAdd(&cursor[ei[E + i]], 1);
        eout[pos] = (ei[i] << 1) | rel;
    }
}

// ---------------------------------------------------------------------------
// Kernel 3: per-node gather-reduce, MERGED (papers then authors in one grid)
// with an unroll-4 software pipeline: all 4 edges' K/V loads issue before any
// compute (8 outstanding vector loads/wave vs 2 before -> latency hidden).
// Tail slots clamp to the last edge and mask the exp to 0.
// ---------------------------------------------------------------------------
__global__ __launch_bounds__(256) void aggregate_kernel(
    const unsigned short* __restrict__ Yp, const unsigned short* __restrict__ Ya,
    const int* __restrict__ rp_p, const int* __restrict__ e_p,
    const int* __restrict__ rp_a, const int* __restrict__ e_a,
    int nnodes, float* __restrict__ agg)      // [2*nnodes][256]
{
    const int wave = threadIdx.x >> 6, lane = threadIdx.x & 63;
    const int node = blockIdx.x * 4 + wave;
    if (node >= 2 * nnodes) return;
    const bool paper = node < nnodes;
    const int n = paper ? node : node - nnodes;

    const unsigned short* Ydst = paper ? Yp : Ya;
    const int dstride = paper ? 1024 : 768;
    const int qoff1   = paper ? 768 : 512;
    const unsigned short* Ys0 = paper ? Ya : Yp;    // rel 0 source
    const int ss0 = paper ? 768 : 1024;
    const unsigned short* Ys1 = Yp;                 // rel 1 source (papers only)
    const int ss1 = 1024;
    const int* rp = paper ? rp_p : rp_a;
    const int* ed = paper ? e_p : e_a;

    const ushort4 q0u = *(const ushort4*)&Ydst[(size_t)n * dstride + 512 + lane * 4];
    const ushort4 q1u = *(const ushort4*)&Ydst[(size_t)n * dstride + qoff1 + lane * 4];
    const float q0x = bf2f(q0u.x), q0y = bf2f(q0u.y), q0z = bf2f(q0u.z), q0w = bf2f(q0u.w);
    const float q1x = bf2f(q1u.x), q1y = bf2f(q1u.y), q1z = bf2f(q1u.z), q1w = bf2f(q1u.w);

    float a0 = 0.f, a1 = 0.f, a2 = 0.f, a3 = 0.f, hs = 0.f;
    const int beg = rp[n], end = rp[n + 1];
    for (int i = beg; i < end; i += 4) {
        ushort4 ku[4], vu[4];
        int rel[4];
        float msk[4];
        #pragma unroll
        for (int u = 0; u < 4; u++) {
            int ii = i + u;
            msk[u] = (ii < end) ? 1.f : 0.f;
            if (ii >= end) ii = end - 1;
            const int e = ed[ii];
            rel[u] = e & 1;
            const size_t src = (size_t)(e >> 1);
            const unsigned short* Ys = rel[u] ? Ys1 : Ys0;
            const int ss = rel[u] ? ss1 : ss0;
            ku[u] = *(const ushort4*)&Ys[src * ss + lane * 4];
            vu[u] = *(const ushort4*)&Ys[src * ss + 256 + lane * 4];
        }
        #pragma unroll
        for (int u = 0; u < 4; u++) {
            float p = (rel[u] ? q1x : q0x) * bf2f(ku[u].x)
                    + (rel[u] ? q1y : q0y) * bf2f(ku[u].y)
                    + (rel[u] ? q1z : q0z) * bf2f(ku[u].z)
                    + (rel[u] ? q1w : q0w) * bf2f(ku[u].w);
            p += __shfl_xor(p, 1);
            p += __shfl_xor(p, 2);
            p += __shfl_xor(p, 4);
            float sc = fminf(fmaxf(p * RSCALE, -5.f), 5.f);
            float a = __expf(sc) * msk[u];
            a0 += bf2f(vu[u].x) * a;
            a1 += bf2f(vu[u].y) * a;
            a2 += bf2f(vu[u].z) * a;
            a3 += bf2f(vu[u].w) * a;
            hs += a;
        }
    }
    hs += __shfl_xor(hs, 8);
    hs += __shfl_xor(hs, 16);
    hs += __shfl_xor(hs, 32);

    const float inv = 1.f / fmaxf(hs * 0.125f, 1e-8f);
    float4 o = make_float4(a0 * inv, a1 * inv, a2 * inv, a3 * inv);
    *(float4*)&agg[(size_t)node * 256 + lane * 4] = o;
}

// ---------------------------------------------------------------------------
// Kernel 4: fused output projection + residual + LayerNorm on MFMA (unchanged).
// ---------------------------------------------------------------------------
__global__ __launch_bounds__(256) void ogemm_ln_kernel(
    const float* agg,                         // [nrows][256] f32 (aliases out)
    const unsigned short* __restrict__ Wt,    // [256][256] bf16, row = out col
    const float* __restrict__ bo, const float* __restrict__ x,
    const float* __restrict__ g, const float* __restrict__ be,
    float* out, int nrows)
{
    __shared__ __align__(16) char smem[64 * 264 * 4];   // 67.6 KB -> 2 blocks/CU
    unsigned short* As_hi = (unsigned short*)smem;      // [64][72]
    unsigned short* As_lo = As_hi + 64 * 72;            // [64][72]
    unsigned short* Bs    = As_lo + 64 * 72;            // [256][72]
    float* Yo = (float*)smem;                           // [64][264] (reused)

    const int t = threadIdx.x;
    const int wave = t >> 6, lane = t & 63;
    const int lquad = lane >> 4, lmod = lane & 15;
    const int row0 = blockIdx.x * 64;
    const int wcol = wave * 64;

    f32x4 acc[4][4];
    #pragma unroll
    for (int i = 0; i < 4; i++)
        #pragma unroll
        for (int j = 0; j < 4; j++) acc[i][j] = (f32x4){0.f, 0.f, 0.f, 0.f};

    for (int k0 = 0; k0 < 256; k0 += 64) {
        #pragma unroll
        for (int p = 0; p < 2; p++) {
            int r = p * 32 + (t >> 3);
            int c8 = (t & 7) * 8;
            float4 v0 = make_float4(0.f, 0.f, 0.f, 0.f), v1 = v0;
            if (row0 + r < nrows) {
                v0 = *(const float4*)&agg[(size_t)(row0 + r) * 256 + k0 + c8];
                v1 = *(const float4*)&agg[(size_t)(row0 + r) * 256 + k0 + c8 + 4];
            }
            ushort4 h0, h1, l0, l1;
            h0.x = f2bf(v0.x); l0.x = f2bf(v0.x - bf2f(h0.x));
            h0.y = f2bf(v0.y); l0.y = f2bf(v0.y - bf2f(h0.y));
            h0.z = f2bf(v0.z); l0.z = f2bf(v0.z - bf2f(h0.z));
            h0.w = f2bf(v0.w); l0.w = f2bf(v0.w - bf2f(h0.w));
            h1.x = f2bf(v1.x); l1.x = f2bf(v1.x - bf2f(h1.x));
            h1.y = f2bf(v1.y); l1.y = f2bf(v1.y - bf2f(h1.y));
            h1.z = f2bf(v1.z); l1.z = f2bf(v1.z - bf2f(h1.z));
            h1.w = f2bf(v1.w); l1.w = f2bf(v1.w - bf2f(h1.w));
            *(ushort4*)&As_hi[r * 72 + c8]     = h0;
            *(ushort4*)&As_hi[r * 72 + c8 + 4] = h1;
            *(ushort4*)&As_lo[r * 72 + c8]     = l0;
            *(ushort4*)&As_lo[r * 72 + c8 + 4] = l1;
        }
        #pragma unroll
        for (int p = 0; p < 8; p++) {
            int r = p * 32 + (t >> 3);
            int c8 = (t & 7) * 8;
            *(float4*)&Bs[r * 72 + c8] = *(const float4*)&Wt[(size_t)r * 256 + k0 + c8];
        }
        __syncthreads();
        #pragma unroll
        for (int ks = 0; ks < 2; ks++) {
            bf16x8 ah[4], al[4], bfr[4];
            #pragma unroll
            for (int i = 0; i < 4; i++) {
                ah[i] = *(const bf16x8*)&As_hi[(i * 16 + lmod) * 72 + ks * 32 + lquad * 8];
                al[i] = *(const bf16x8*)&As_lo[(i * 16 + lmod) * 72 + ks * 32 + lquad * 8];
            }
            #pragma unroll
            for (int j = 0; j < 4; j++)
                bfr[j] = *(const bf16x8*)&Bs[(wcol + j * 16 + lmod) * 72 + ks * 32 + lquad * 8];
            #pragma unroll
            for (int i = 0; i < 4; i++)
                #pragma unroll
                for (int j = 0; j < 4; j++) {
                    acc[i][j] = __builtin_amdgcn_mfma_f32_16x16x32_bf16(ah[i], bfr[j], acc[i][j], 0, 0, 0);
                    acc[i][j] = __builtin_amdgcn_mfma_f32_16x16x32_bf16(al[i], bfr[j], acc[i][j], 0, 0, 0);
                }
        }
        __syncthreads();
    }

    float bj[4];
    #pragma unroll
    for (int j = 0; j < 4; j++) bj[j] = bo[wcol + j * 16 + lmod];
    #pragma unroll
    for (int i = 0; i < 4; i++)
        #pragma unroll
        for (int j = 0; j < 4; j++)
            #pragma unroll
            for (int rg = 0; rg < 4; rg++)
                Yo[(i * 16 + lquad * 4 + rg) * 264 + wcol + j * 16 + lmod] = acc[i][j][rg] + bj[j];
    __syncthreads();

    const float4 gv  = *(const float4*)&g[lane * 4];
    const float4 bev = *(const float4*)&be[lane * 4];
    #pragma unroll 1
    for (int ii = 0; ii < 16; ii++) {
        int lr = wave * 16 + ii;
        int r = row0 + lr;
        if (r >= nrows) break;
        float4 y = *(const float4*)&Yo[lr * 264 + lane * 4];
        float4 xv = *(const float4*)&x[(size_t)r * 256 + lane * 4];
        y.x += xv.x; y.y += xv.y; y.z += xv.z; y.w += xv.w;
        float sum = y.x + y.y + y.z + y.w;
        for (int o = 1; o < 64; o <<= 1) sum += __shfl_xor(sum, o);
        float m = sum * (1.f / 256.f);
        float d0 = y.x - m, d1 = y.y - m, d2 = y.z - m, d3 = y.w - m;
        float vs = d0 * d0 + d1 * d1 + d2 * d2 + d3 * d3;
        for (int o = 1; o < 64; o <<= 1) vs += __shfl_xor(vs, o);
        float rstd = rsqrtf(vs * (1.f / 256.f) + 1e-5f);
        float4 o4;
        o4.x = d0 * rstd * gv.x + bev.x;
        o4.y = d1 * rstd * gv.y + bev.y;
        o4.z = d2 * rstd * gv.z + bev.z;
        o4.w = d3 * rstd * gv.w + bev.w;
        *(float4*)&out[(size_t)r * 256 + lane * 4] = o4;
    }
}

// ---------------------------------------------------------------------------
extern "C" void kernel_launch(void* const* d_in, const int* in_sizes, int n_in,
                              void* d_out, int out_size, void* d_ws, size_t ws_size,
                              hipStream_t stream)
{
    const float* x_p  = (const float*)d_in[0];
    const float* x_a  = (const float*)d_in[1];
    const float* Wk_p = (const float*)d_in[2];
    const float* bk_p = (const float*)d_in[3];
    const float* Wq_p = (const float*)d_in[4];
    const float* bq_p = (const float*)d_in[5];
    const float* Wv_p = (const float*)d_in[6];
    const float* bv_p = (const float*)d_in[7];
    const float* Wo_p = (const float*)d_in[8];
    const float* bo_p = (const float*)d_in[9];
    const float* g_p  = (const float*)d_in[10];
    const float* be_p = (const float*)d_in[11];
    const float* Wk_a = (const float*)d_in[12];
    const float* bk_a = (const float*)d_in[13];
    const float* Wq_a = (const float*)d_in[14];
    const float* bq_a = (const float*)d_in[15];
    const float* Wv_a = (const float*)d_in[16];
    const float* bv_a = (const float*)d_in[17];
    const float* Wo_a = (const float*)d_in[18];
    const float* bo_a = (const float*)d_in[19];
    const float* g_a  = (const float*)d_in[20];
    const float* be_a = (const float*)d_in[21];
    const float* R_w  = (const float*)d_in[22];
    const int*   ei_w = (const int*)d_in[23];
    const float* R_c  = (const float*)d_in[24];
    const int*   ei_c = (const int*)d_in[25];
    const float* R_wb = (const float*)d_in[26];
    const int*   ei_wb= (const int*)d_in[27];

    const int N   = in_sizes[0] / 256;
    const int Ew  = in_sizes[23] / 2;
    const int Ec  = in_sizes[25] / 2;
    const int Ewb = in_sizes[27] / 2;

    size_t off = 0;
    auto walloc = [&](size_t bytes) {
        void* p = (char*)d_ws + off;
        off += (bytes + 255) & ~(size_t)255;
        return p;
    };
    unsigned short* Xb_p = (unsigned short*)walloc((size_t)N * 256 * 2);
    unsigned short* Xb_a = (unsigned short*)walloc((size_t)N * 256 * 2);
    unsigned short* Wt_p = (unsigned short*)walloc((size_t)1024 * 256 * 2);
    unsigned short* Wt_a = (unsigned short*)walloc((size_t)768 * 256 * 2);
    unsigned short* Wto_p = (unsigned short*)walloc((size_t)256 * 256 * 2);
    unsigned short* Wto_a = (unsigned short*)walloc((size_t)256 * 256 * 2);
    float* bcat_p = (float*)walloc(1024 * 4);
    float* bcat_a = (float*)walloc(768 * 4);
    unsigned short* Y_p = (unsigned short*)walloc((size_t)N * 1024 * 2);
    unsigned short* Y_a = (unsigned short*)walloc((size_t)N * 768 * 2);
    int* cnt_p = (int*)walloc((size_t)N * 4);        // histogram -> cursor
    int* rp_p  = (int*)walloc((size_t)(N + 1) * 4);
    int* e_p   = (int*)walloc((size_t)(Ew + Ec) * 4);
    int* cnt_a = (int*)walloc((size_t)N * 4);
    int* rp_a  = (int*)walloc((size_t)(N + 1) * 4);
    int* e_a   = (int*)walloc((size_t)Ewb * 4);
    int* bsum  = (int*)walloc(1024 * 4);

    float* agg_p = (float*)d_out;
    float* agg_a = (float*)d_out + (size_t)N * 256;

    const int nb = (N + 1023) / 1024;   // scan blocks (98 for N=100k)

    hipMemsetAsync(cnt_p, 0, (size_t)N * 4, stream);
    hipMemsetAsync(cnt_a, 0, (size_t)N * 4, stream);

    {
        int total = 1024 * 256 + 768 * 256 + 1024 + 768;
        prep_weights<<<(total + 255) / 256, 256, 0, stream>>>(
            Wk_p, Wv_p, Wq_p, R_w, R_c, bk_p, bv_p, bq_p,
            Wk_a, Wv_a, Wq_a, R_wb, bk_a, bv_a, bq_a,
            Wt_p, bcat_p, Wt_a, bcat_a);
        prep_wo<<<(2 * 256 * 256) / 256, 256, 0, stream>>>(Wo_p, Wo_a, Wto_p, Wto_a);
        convert_bf16<<<2048, 256, 0, stream>>>(x_p, x_a, Xb_p, Xb_a, N * 32);
    }

    // histograms (independent of GEMMs)
    hist_kernel<<<(Ew + 255) / 256, 256, 0, stream>>>(ei_w, Ew, cnt_p);
    hist_kernel<<<(Ec + 255) / 256, 256, 0, stream>>>(ei_c, Ec, cnt_p);
    hist_kernel<<<(Ewb + 255) / 256, 256, 0, stream>>>(ei_wb, Ewb, cnt_a);

    // projections (MFMA)
    {
        int rb = (N + 127) / 128;
        gemm_mfma<<<8 * rb, 256, 0, stream>>>(Xb_p, Wt_p, bcat_p, Y_p, N, 1024);
        gemm_mfma<<<6 * rb, 256, 0, stream>>>(Xb_a, Wt_a, bcat_a, Y_a, N, 768);
    }

    // CSR: papers
    scan1<<<nb, 256, 0, stream>>>(cnt_p, N, bsum);
    scan2<<<1, 256, 0, stream>>>(bsum, nb);
    scan3<<<nb, 256, 0, stream>>>(cnt_p, N, bsum, rp_p);
    scatter_kernel<<<(Ew + 255) / 256, 256, 0, stream>>>(ei_w, Ew, 0, cnt_p, e_p);
    scatter_kernel<<<(Ec + 255) / 256, 256, 0, stream>>>(ei_c, Ec, 1, cnt_p, e_p);
    // CSR: authors
    scan1<<<nb, 256, 0, stream>>>(cnt_a, N, bsum);
    scan2<<<1, 256, 0, stream>>>(bsum, nb);
    scan3<<<nb, 256, 0, stream>>>(cnt_a, N, bsum, rp_a);
    scatter_kernel<<<(Ewb + 255) / 256, 256, 0, stream>>>(ei_wb, Ewb, 0, cnt_a, e_a);

    // merged aggregate: papers (nodes 0..N-1) + authors (nodes N..2N-1)
    aggregate_kernel<<<(2 * N + 3) / 4, 256, 0, stream>>>(
        Y_p, Y_a, rp_p, e_p, rp_a, e_a, N, agg_p);

    // fused output projection + residual + LayerNorm (in-place over agg)
    ogemm_ln_kernel<<<(N + 63) / 64, 256, 0, stream>>>(agg_p, Wto_p, bo_p, x_p, g_p, be_p, agg_p, N);
    ogemm_ln_kernel<<<(N + 63) / 64, 256, 0, stream>>>(agg_a, Wto_a, bo_a, x_a, g_a, be_a, agg_a, N);
}